// Round 1
// 505.588 us; speedup vs baseline: 1.0459x; 1.0459x over previous
//
#include <hip/hip_runtime.h>

#define LOG2E 1.4426950408889634f

typedef _Float16 half8 __attribute__((ext_vector_type(8)));
typedef float floatx16 __attribute__((ext_vector_type(16)));

// ---- global -> LDS direct copy, 16B per lane --------------------------------
__device__ __forceinline__ void g2l16(const void* g, void* l) {
  __builtin_amdgcn_global_load_lds(
      (__attribute__((address_space(1))) void*)(unsigned long long)(g),
      (__attribute__((address_space(3))) void*)(unsigned int)(unsigned long long)(l),
      16, 0, 0);
}

// ---- prep: codebook fp32 -> fp16 (two layouts) + c2 scale -------------------
// ws layout:
//   cb16  [8][256][128] _Float16   @ 0        (512 KB)  codeword-major
//   cbT   [8][128][256] _Float16   @ 524288   (512 KB)  d-major, codeword idx
//                                                  PERMUTED: kp = swap bits 2,3
//   c2s   [8][256] float           @ 1048576  (8 KB)    ||c||^2 * invT * log2e
__global__ __launch_bounds__(128, 4) void prep_kernel(
    const float* __restrict__ cb, const int* __restrict__ tptr,
    _Float16* __restrict__ cb16, _Float16* __restrict__ cbT,
    float* __restrict__ c2s) {
  int mk = blockIdx.x;            // 0..2047 = m*256 + k
  int m = mk >> 8, k = mk & 255;
  int d = threadIdx.x;            // 0..127
  float v = cb[(size_t)mk * 128 + d];
  _Float16 h = (_Float16)v;
  cb16[(size_t)mk * 128 + d] = h;
  int kp = (k & 243) | ((k & 4) << 1) | ((k & 8) >> 1);   // swap bits 2<->3
  cbT[((size_t)m * 128 + d) * 256 + kp] = h;
  float sq = v * v;
#pragma unroll
  for (int o = 0; o < 6; ++o) sq += __shfl_xor(sq, 1 << o, 64);
  __shared__ float part[2];
  if ((threadIdx.x & 63) == 0) part[threadIdx.x >> 6] = sq;
  __syncthreads();
  if (threadIdx.x == 0) {
    float invT = 1.0f / (float)tptr[0];
    c2s[mk] = (part[0] + part[1]) * invT * LOG2E;
  }
}

// ---- main fused kernel ------------------------------------------------------
// Swapped-operand form: GEMM1 computes S^T = C * X^T, so each lane owns the
// scores (128 of 256 codewords, bit2==h) of ONE x-row -> softmax is lane-local
// and P stays in registers, feeding GEMM2 (Out^T = C^T_perm * P^T) directly.
// LDS: one 64 KB buffer, staged whole (cb16[m], then reused for cbT[m]).
// 3 barriers per block total.
__global__ __launch_bounds__(256, 2) void pq_kernel(
    const float* __restrict__ x, const int* __restrict__ tptr,
    const _Float16* __restrict__ cb16, const _Float16* __restrict__ cbT,
    const float* __restrict__ c2s, float* __restrict__ out) {
  __shared__ __align__(16) _Float16 smem[32768];   // 64 KB
  char* sb = (char*)smem;

  const int m = blockIdx.x & 7;        // XCD-affine subspace
  const int tile = blockIdx.x >> 3;
  const int tid = threadIdx.x;
  const int w = tid >> 6;
  const int lane = tid & 63;
  const int n2 = lane & 31;            // x-row within wave tile (MFMA col)
  const int h = lane >> 5;             // k-half selector / codeword bit2
  const int xrow = tile * 128 + w * 32 + n2;

  const char* cbm  = (const char*)(cb16 + (size_t)m * 256 * 128);
  const char* cbtm = (const char*)(cbT  + (size_t)m * 128 * 256);

  // ---- stage cb16[m]: 64 KB, linear LDS dest, XOR-swizzled global source ----
  // read swizzle is addr ^ ((row&7)<<4) with row = 256B codeword row; staging
  // pre-applies the same involution on the source so reads land correctly.
  {
    const int swz = ((tid >> 4) & 7) << 4;      // row&7 of this thread's chunk
#pragma unroll
    for (int i = 0; i < 16; ++i) {
      int L = (i * 256 + tid) * 16;
      g2l16(cbm + (L ^ swz), sb + L);
    }
  }

  // ---- x loads, batch 0 (kc 0..3): 8 contiguous floats per lane per kc -----
  const float* xp = x + (size_t)xrow * 1024 + m * 128 + h * 8;
  float4 xa[8], xb[8];
#pragma unroll
  for (int kc = 0; kc < 4; ++kc) {
    xa[kc] = *(const float4*)(xp + kc * 16);
    xb[kc] = *(const float4*)(xp + kc * 16 + 4);
  }

  floatx16 acc[8];
#pragma unroll
  for (int t = 0; t < 8; ++t)
#pragma unroll
    for (int i = 0; i < 16; ++i) acc[t][i] = 0.0f;

  __syncthreads();   // cb16 staged (+ batch0 x in flight drained)

  const int rsw = (n2 & 7) << 4;   // LDS read swizzle (row&7 == n2&7)

  // ---------------- GEMM1: S^T[256 k x 32 rows] = C * X^T (x split hi+lo) ---
#pragma unroll
  for (int kc = 0; kc < 8; ++kc) {
    if (kc == 2) {   // issue batch 1 under the MFMA stream
#pragma unroll
      for (int k2 = 4; k2 < 8; ++k2) {
        xa[k2] = *(const float4*)(xp + k2 * 16);
        xb[k2] = *(const float4*)(xp + k2 * 16 + 4);
      }
    }
    float f[8] = {xa[kc].x, xa[kc].y, xa[kc].z, xa[kc].w,
                  xb[kc].x, xb[kc].y, xb[kc].z, xb[kc].w};
    half8 bhi, blo;
#pragma unroll
    for (int j = 0; j < 8; ++j) {
      _Float16 hi = (_Float16)f[j];
      bhi[j] = hi;
      blo[j] = (_Float16)(f[j] - (float)hi);
    }
#pragma unroll
    for (int t = 0; t < 8; ++t) {
      int addr = (((t * 32 + n2) * 256) + kc * 32 + h * 16) ^ rsw;
      half8 a = *(const half8*)(sb + addr);
      acc[t] = __builtin_amdgcn_mfma_f32_32x32x16_f16(a, bhi, acc[t], 0, 0, 0);
      acc[t] = __builtin_amdgcn_mfma_f32_32x32x16_f16(a, blo, acc[t], 0, 0, 0);
    }
  }

  __syncthreads();   // all waves done reading cb16 region

  // ---- stage cbT[m] over the same buffer; latency hides under softmax ------
  {
    const int swz2 = ((tid >> 5) & 7) << 4;     // row&7 for 512B d-rows
#pragma unroll
    for (int i = 0; i < 16; ++i) {
      int L = (i * 256 + tid) * 16;
      g2l16(cbtm + (L ^ swz2), sb + L);
    }
  }

  // ---------------- softmax: fully in-register, 1 shuffle each for max/sum --
  // acc[t][r] = score for x-row n2, codeword k = t*32 + (r&3) + 8*(r>>2) + 4h
  const float invT = 1.0f / (float)tptr[0];
  const float kappa = 2.0f * invT * LOG2E;
  const float4* c2p = (const float4*)(c2s + m * 256) + h;

  float mx = -3.0e38f;
#pragma unroll
  for (int t = 0; t < 8; ++t) {
    float4 cq[4];
#pragma unroll
    for (int q = 0; q < 4; ++q) cq[q] = c2p[t * 8 + q * 2];
    float cf[16] = {cq[0].x, cq[0].y, cq[0].z, cq[0].w,
                    cq[1].x, cq[1].y, cq[1].z, cq[1].w,
                    cq[2].x, cq[2].y, cq[2].z, cq[2].w,
                    cq[3].x, cq[3].y, cq[3].z, cq[3].w};
#pragma unroll
    for (int r = 0; r < 16; ++r) {
      float v = acc[t][r] * kappa - cf[r];
      acc[t][r] = v;
      mx = fmaxf(mx, v);
    }
  }
  mx = fmaxf(mx, __shfl_xor(mx, 32));    // combine with partner half

  float s = 0.0f;
#pragma unroll
  for (int t = 0; t < 8; ++t)
#pragma unroll
    for (int r = 0; r < 16; ++r) {
      float e = exp2f(acc[t][r] - mx);
      acc[t][r] = e;
      s += e;
    }
  s += __shfl_xor(s, 32);
  const float is = 1.0f / s;

  // P -> fp16 in register; reg order r matches GEMM2 fragment order exactly:
  // fragment for chunk kc = regs 8*(kc&1)..+7 of tile t = kc>>1.
  half8 p0[8], p1[8];
#pragma unroll
  for (int t = 0; t < 8; ++t) {
#pragma unroll
    for (int r = 0; r < 8; ++r) p0[t][r] = (_Float16)(acc[t][r] * is);
#pragma unroll
    for (int r = 0; r < 8; ++r) p1[t][r] = (_Float16)(acc[t][8 + r] * is);
  }

  __syncthreads();   // cbT staged

  // ---------------- GEMM2: Out^T[128 d x 32 rows] = C^T_perm * P^T ----------
  floatx16 acc2[4];
#pragma unroll
  for (int t = 0; t < 4; ++t)
#pragma unroll
    for (int i = 0; i < 16; ++i) acc2[t][i] = 0.0f;

#pragma unroll
  for (int kc = 0; kc < 16; ++kc) {
    half8 b = (kc & 1) ? p1[kc >> 1] : p0[kc >> 1];
#pragma unroll
    for (int dt = 0; dt < 4; ++dt) {
      int addr = (((dt * 32 + n2) * 512) + kc * 32 + h * 16) ^ rsw;
      half8 a = *(const half8*)(sb + addr);
      acc2[dt] = __builtin_amdgcn_mfma_f32_32x32x16_f16(a, b, acc2[dt], 0, 0, 0);
    }
  }

  // ---------------- epilogue: direct coalesced float4 stores ----------------
  // acc2[dt][r] = Out[xrow][m*128 + dt*32 + (r&3) + 8*(r>>2) + 4h]
  float* op = out + (size_t)xrow * 1024 + m * 128 + h * 4;
#pragma unroll
  for (int dt = 0; dt < 4; ++dt)
#pragma unroll
    for (int q = 0; q < 4; ++q) {
      float4 v = {acc2[dt][q * 4 + 0], acc2[dt][q * 4 + 1],
                  acc2[dt][q * 4 + 2], acc2[dt][q * 4 + 3]};
      *(float4*)(op + dt * 32 + q * 8) = v;
    }
}

extern "C" void kernel_launch(void* const* d_in, const int* in_sizes, int n_in,
                              void* d_out, int out_size, void* d_ws, size_t ws_size,
                              hipStream_t stream) {
  const float* x = (const float*)d_in[0];
  const float* cb = (const float*)d_in[1];
  const int* tptr = (const int*)d_in[2];

  _Float16* cb16 = (_Float16*)d_ws;
  _Float16* cbT = (_Float16*)((char*)d_ws + 524288);
  float* c2s = (float*)((char*)d_ws + 1048576);
  float* out = (float*)d_out;

  prep_kernel<<<2048, 128, 0, stream>>>(cb, tptr, cb16, cbT, c2s);
  pq_kernel<<<4096, 256, 0, stream>>>(x, tptr, cb16, cbT, c2s, out);
}